// Round 8
// baseline (173.043 us; speedup 1.0000x reference)
//
#include <hip/hip_runtime.h>
#include <hip/hip_bf16.h>
#include <cstdint>
#include <cstddef>

#define B_SZ   2
#define T_CTX  2048
#define DIM_C  1024
#define NHEAD  16
#define HD     64
#define NBH    (B_SZ*NHEAD)

typedef __attribute__((ext_vector_type(8))) short short8;
typedef __attribute__((ext_vector_type(4))) float f32x4;
typedef __attribute__((ext_vector_type(16))) float f32x16;

union BV8 { short8 s; __hip_bfloat16 h[8]; unsigned short u[8]; };
union U32x4 { uint32_t u[4]; short8 s8; };

#define GLD16(gp, lp) \
  __builtin_amdgcn_global_load_lds((const __attribute__((address_space(1))) void*)(gp), \
                                   (__attribute__((address_space(3))) void*)(lp), 16, 0, 0)

// pack two f32 -> bf16 pair (lo = first arg), pure IR (hazard-safe feed into MFMA)
__device__ inline uint32_t pkbf(float a, float b) {
  union { __hip_bfloat16 h; unsigned short u; } ua, ub;
  ua.h = __float2bfloat16(a);
  ub.h = __float2bfloat16(b);
  return ((uint32_t)ub.u << 16) | (uint32_t)ua.u;
}

// ---------------- fp32 -> bf16 convert ----------------
__global__ __launch_bounds__(256) void cvt_f32_bf16(const float* __restrict__ in,
                                                    __hip_bfloat16* __restrict__ out,
                                                    int n4) {
  int i = blockIdx.x * 256 + threadIdx.x;
  if (i >= n4) return;
  float4 v = reinterpret_cast<const float4*>(in)[i];
  BV8 o;
  o.h[0] = __float2bfloat16(v.x);
  o.h[1] = __float2bfloat16(v.y);
  o.h[2] = __float2bfloat16(v.z);
  o.h[3] = __float2bfloat16(v.w);
  ushort4 st = { o.u[0], o.u[1], o.u[2], o.u[3] };
  reinterpret_cast<ushort4*>(out)[i] = st;
}

// ---------------- bf16 GEMM, C = A[M,K] * Bt[N,K]^T ----------------
template <typename OutT>
__global__ __launch_bounds__(256) void gemm_bt(const __hip_bfloat16* __restrict__ A,
                                               const __hip_bfloat16* __restrict__ Bt,
                                               OutT* __restrict__ C,
                                               int M, int N, int K) {
  __shared__ __align__(16) __hip_bfloat16 As[128 * 32];
  __shared__ __align__(16) __hip_bfloat16 Bs[128 * 32];
  const int tid = threadIdx.x;
  const int w = tid >> 6, l = tid & 63;
  const int l15 = l & 15, l4 = l >> 4;
  const int wr = w >> 1, wc = w & 1;
  const long bm = (long)blockIdx.y * 128;
  const long bn = (long)blockIdx.x * 128;

  f32x4 acc[4][4] = {};

  const int srow = tid >> 2;
  const int scol = (tid & 3) * 16;
  char* AsB = (char*)As;
  char* BsB = (char*)Bs;
  const char* Ab  = (const char*)A;
  const char* Btb = (const char*)Bt;

  for (int kt = 0; kt < K; kt += 32) {
    __syncthreads();
#pragma unroll
    for (int it = 0; it < 2; ++it) {
      long arow = bm + it * 64 + srow;
      GLD16(Ab + (arow * K + kt) * 2 + scol, AsB + it * 4096 + w * 1024);
      long brow = bn + it * 64 + srow;
      GLD16(Btb + (brow * K + kt) * 2 + scol, BsB + it * 4096 + w * 1024);
    }
    __syncthreads();
    short8 aF[4], bF[4];
#pragma unroll
    for (int m = 0; m < 4; ++m)
      aF[m] = *(const short8*)(AsB + (wr * 64 + m * 16 + l15) * 64 + l4 * 16);
#pragma unroll
    for (int n = 0; n < 4; ++n)
      bF[n] = *(const short8*)(BsB + (wc * 64 + n * 16 + l15) * 64 + l4 * 16);
#pragma unroll
    for (int m = 0; m < 4; ++m)
#pragma unroll
      for (int n = 0; n < 4; ++n)
        acc[m][n] = __builtin_amdgcn_mfma_f32_16x16x32_bf16(aF[m], bF[n], acc[m][n], 0, 0, 0);
  }

#pragma unroll
  for (int m = 0; m < 4; ++m)
#pragma unroll
    for (int n = 0; n < 4; ++n)
#pragma unroll
      for (int r = 0; r < 4; ++r) {
        long row = bm + wr * 64 + m * 16 + l4 * 4 + r;
        long col = bn + wc * 64 + n * 16 + l15;
        float v = acc[m][n][r];
        if constexpr (sizeof(OutT) == 2) {
          C[row * N + col] = __float2bfloat16(v);
        } else {
          C[row * N + col] = v;
        }
      }
}

// ---------------- RoPE + repack ----------------
// Q scale folds softmax 1/8 AND log2(e) so attention softmax can use exp2 natively.
__global__ __launch_bounds__(256) void rope_pack(const __hip_bfloat16* __restrict__ qkv,
                                                 __hip_bfloat16* __restrict__ Qb,
                                                 __hip_bfloat16* __restrict__ Kb,
                                                 __hip_bfloat16* __restrict__ VTb) {
  __shared__ __hip_bfloat16 vt[64][72];
  const int bh = blockIdx.x;
  const int b = bh >> 4, h = bh & 15;
  const int t0 = blockIdx.y * 64;
  const int tid = threadIdx.x;
  const float QSCL = 0.125f * 1.4426950408889634f;

#pragma unroll
  for (int rep = 0; rep < 2; ++rep) {
    int idx = rep * 256 + tid;
    int tt = idx >> 3;
    int d0 = (idx & 7) * 8;
    int t = t0 + tt;
    size_t src = ((size_t)(b * T_CTX + t)) * 3072 + h * 64 + d0;
    BV8 qv, kv, vv, qo, ko;
    qv.s = *(const short8*)(qkv + src);
    kv.s = *(const short8*)(qkv + src + 1024);
    vv.s = *(const short8*)(qkv + src + 2048);
#pragma unroll
    for (int p = 0; p < 4; ++p) {
      int i = (d0 >> 1) + p;
      float inv = exp2f(-13.287712379549449f * ((float)(2 * i) * (1.0f / 64.0f)));
      float ang = (float)t * inv;
      float sn, cn;
      sincosf(ang, &sn, &cn);
      float q1 = __bfloat162float(qv.h[2 * p]);
      float q2 = __bfloat162float(qv.h[2 * p + 1]);
      float k1 = __bfloat162float(kv.h[2 * p]);
      float k2 = __bfloat162float(kv.h[2 * p + 1]);
      qo.h[2 * p]     = __float2bfloat16((q1 * cn - q2 * sn) * QSCL);
      qo.h[2 * p + 1] = __float2bfloat16((q1 * sn + q2 * cn) * QSCL);
      ko.h[2 * p]     = __float2bfloat16(k1 * cn - k2 * sn);
      ko.h[2 * p + 1] = __float2bfloat16(k1 * sn + k2 * cn);
    }
    size_t dst = ((size_t)bh * T_CTX + t) * 64 + d0;
    *(short8*)(Qb + dst) = qo.s;
    *(short8*)(Kb + dst) = ko.s;
#pragma unroll
    for (int j = 0; j < 8; ++j) vt[d0 + j][tt] = vv.h[j];
  }
  __syncthreads();
#pragma unroll
  for (int rep = 0; rep < 2; ++rep) {
    int idx = rep * 256 + tid;
    int d = idx >> 3;
    int toff = (idx & 7) * 8;
    BV8 o;
#pragma unroll
    for (int j = 0; j < 8; ++j) o.h[j] = vt[d][toff + j];
    *(short8*)(VTb + ((size_t)bh * 64 + d) * T_CTX + t0 + toff) = o.s;
  }
}

// ---------------- flash attention (causal), 32x32 MFMA, LDS-FREE ----------------
// All MFMA fragments are per-lane 16B global loads served by L1/L2 (K/V per-XCD
// working set ~2MB fits L2; lin%8==bh%8 pins bh to an XCD). No LDS, no barriers,
// no vmcnt(0) drain — each wave is an independent load->MFMA pipeline.
// 4 waves/block (q-slab 128, tiles shared via L1). Per-wave loop bound = own diagonal.
// Swapped QK^T (S^T = mfma(K, Q^T)), fixed-base exp2 softmax (no online max).
__global__ __launch_bounds__(256) void flash_attn(const __hip_bfloat16* __restrict__ Qb,
                                                  const __hip_bfloat16* __restrict__ Kb,
                                                  const __hip_bfloat16* __restrict__ VTb,
                                                  __hip_bfloat16* __restrict__ Y) {
  const int bh = blockIdx.x;
  const int b = bh >> 4, h = bh & 15;
  const int w = threadIdx.x >> 6;
  const int l = threadIdx.x & 63;
  const int l31 = l & 31, hh = l >> 5;
  const int qw = (15 - (int)blockIdx.y) * 128 + w * 32;  // longest slabs first

  // Q as B-operand: lane q = qw + l31, contraction d = dblk*16 + hh*8 + j
  short8 qB[4];
  {
    const __hip_bfloat16* qptr = Qb + ((size_t)bh * T_CTX + qw + l31) * 64 + hh * 8;
#pragma unroll
    for (int dblk = 0; dblk < 4; ++dblk)
      qB[dblk] = *(const short8*)(qptr + dblk * 16);
  }

  f32x16 o0 = {}, o1 = {};  // O^T: d = dt*32 + (r&3) + 8*(r>>2) + 4*hh, q = l31
  float lrow = 0.0f;

  // per-lane fragment base pointers (advance by tile inside the loop)
  const __hip_bfloat16* kptr = Kb + ((size_t)bh * T_CTX + l31) * 64 + hh * 8;
  const __hip_bfloat16* vptr = VTb + ((size_t)bh * 64 + l31) * T_CTX + hh * 8;

  const int tmax = qw >> 6;
  for (int t = 0; t <= tmax; ++t) {
    const int kv0 = t << 6;

    // K fragments: rows kv0+l31 and kv0+32+l31, elem col dblk*16 + hh*8
    short8 kA0[4], kA1[4];
    {
      const __hip_bfloat16* k0 = kptr + (size_t)kv0 * 64;
      const __hip_bfloat16* k1 = k0 + 32 * 64;
#pragma unroll
      for (int dblk = 0; dblk < 4; ++dblk) {
        kA0[dblk] = *(const short8*)(k0 + dblk * 16);
        kA1[dblk] = *(const short8*)(k1 + dblk * 16);
      }
    }

    // QK^T: sT0 k = kv0 + (r&3)+8*(r>>2)+4*hh, sT1 same +32; q = qw + l31
    f32x16 sT0 = {}, sT1 = {};
#pragma unroll
    for (int dblk = 0; dblk < 4; ++dblk) {
      __builtin_amdgcn_s_setprio(1);
      sT0 = __builtin_amdgcn_mfma_f32_32x32x16_bf16(kA0[dblk], qB[dblk], sT0, 0, 0, 0);
      sT1 = __builtin_amdgcn_mfma_f32_32x32x16_bf16(kA1[dblk], qB[dblk], sT1, 0, 0, 0);
      __builtin_amdgcn_s_setprio(0);
    }

    // V fragments issued now: L2 latency hides under the softmax VALU chain.
    // A-operand rows d = l31 (+32), contraction k = kv0 + ks*16 + hh*8 + j
    short8 vA0[4], vA1[4];
    {
      const __hip_bfloat16* v0 = vptr + kv0;
      const __hip_bfloat16* v1 = v0 + 32 * T_CTX;
#pragma unroll
      for (int ks = 0; ks < 4; ++ks) {
        vA0[ks] = *(const short8*)(v0 + ks * 16);
        vA1[ks] = *(const short8*)(v1 + ks * 16);
      }
    }

    if (kv0 + 63 > qw) {  // diagonal tile: causal mask
      int q = qw + l31;
#pragma unroll
      for (int r = 0; r < 16; ++r) {
        int k0 = kv0 + 4 * hh + (r & 3) + 8 * (r >> 2);
        sT0[r] = (k0 > q) ? -1e30f : sT0[r];
        sT1[r] = (k0 + 32 > q) ? -1e30f : sT1[r];
      }
    }

    // --- fixed-base softmax: P = exp2(s), no max tracking, no cross-lane ops ---
    float s8[8];
#pragma unroll
    for (int i = 0; i < 8; ++i) {
      sT0[i]     = __builtin_amdgcn_exp2f(sT0[i]);
      sT0[i + 8] = __builtin_amdgcn_exp2f(sT0[i + 8]);
      sT1[i]     = __builtin_amdgcn_exp2f(sT1[i]);
      sT1[i + 8] = __builtin_amdgcn_exp2f(sT1[i + 8]);
      s8[i] = (sT0[i] + sT0[i + 8]) + (sT1[i] + sT1[i + 8]);
    }
    lrow += ((s8[0] + s8[1]) + (s8[2] + s8[3])) + ((s8[4] + s8[5]) + (s8[6] + s8[7]));

    // --- P -> bf16 pairs (IR pack) ---
    uint32_t wk0[8], wk1[8];
#pragma unroll
    for (int i = 0; i < 8; ++i) {
      wk0[i] = pkbf(sT0[2 * i], sT0[2 * i + 1]);
      wk1[i] = pkbf(sT1[2 * i], sT1[2 * i + 1]);
    }

    // PV: O^T[dt] += mfma(A=V^T, B=P^T), 4 k-slices of 16.
    // B-frag needs k = ks*16 + hh*8 + j; lane owns interleaved quads -> one
    // pre-selected __shfl_xor(32) pair per slice completes the fragment.
#pragma unroll
    for (int ks = 0; ks < 4; ++ks) {
      const uint32_t* wk = (ks < 2) ? wk0 : wk1;
      const int base = (ks & 1) * 4;
      uint32_t own0 = wk[base + 0], own1 = wk[base + 1];
      uint32_t own2 = wk[base + 2], own3 = wk[base + 3];
      uint32_t e0 = (uint32_t)__shfl_xor((int)(hh ? own0 : own2), 32);
      uint32_t e1 = (uint32_t)__shfl_xor((int)(hh ? own1 : own3), 32);
      U32x4 u;
      u.u[0] = hh ? e0 : own0;
      u.u[1] = hh ? e1 : own1;
      u.u[2] = hh ? own2 : e0;
      u.u[3] = hh ? own3 : e1;
      __builtin_amdgcn_s_setprio(1);
      o0 = __builtin_amdgcn_mfma_f32_32x32x16_bf16(vA0[ks], u.s8, o0, 0, 0, 0);
      o1 = __builtin_amdgcn_mfma_f32_32x32x16_bf16(vA1[ks], u.s8, o1, 0, 0, 0);
      __builtin_amdgcn_s_setprio(0);
    }
  }

  // epilogue: single cross-lane l-reduce, then Y[b][q][h*64+d], d = dt*32 + 8*e + 4*hh + i
  lrow += __shfl_xor(lrow, 32);
  float inv = 1.0f / lrow;
  size_t rowoff = ((size_t)(b * T_CTX + qw + l31)) * DIM_C + h * 64;
#pragma unroll
  for (int dt = 0; dt < 2; ++dt)
#pragma unroll
    for (int e = 0; e < 4; ++e) {
      union { ushort4 v; unsigned short us[4]; } st;
#pragma unroll
      for (int i = 0; i < 4; ++i) {
        union { __hip_bfloat16 h2; unsigned short u; } cv;
        float val = (dt ? o1[e * 4 + i] : o0[e * 4 + i]) * inv;
        cv.h2 = __float2bfloat16(val);
        st.us[i] = cv.u;
      }
      *(ushort4*)(Y + rowoff + dt * 32 + 8 * e + 4 * hh) = st.v;
    }
}

// ---------------- launcher ----------------
extern "C" void kernel_launch(void* const* d_in, const int* in_sizes, int n_in,
                              void* d_out, int out_size, void* d_ws, size_t ws_size,
                              hipStream_t stream) {
  const float* x     = (const float*)d_in[0];
  const float* qkv_w = (const float*)d_in[1];
  const float* out_w = (const float*)d_in[2];
  float* out = (float*)d_out;

  char* ws = (char*)d_ws;
  const size_t MB = 1024 * 1024;
  __hip_bfloat16* xb    = (__hip_bfloat16*)(ws + 0 * MB);
  __hip_bfloat16* wqkvb = (__hip_bfloat16*)(ws + 8 * MB);
  __hip_bfloat16* woutb = (__hip_bfloat16*)(ws + 14 * MB);
  __hip_bfloat16* qkvb  = (__hip_bfloat16*)(ws + 16 * MB);
  __hip_bfloat16* Qb    = (__hip_bfloat16*)(ws + 40 * MB);
  __hip_bfloat16* Kb    = (__hip_bfloat16*)(ws + 48 * MB);
  __hip_bfloat16* VTb   = (__hip_bfloat16*)(ws + 56 * MB);
  __hip_bfloat16* yb    = (__hip_bfloat16*)(ws + 64 * MB);

  cvt_f32_bf16<<<4096, 256, 0, stream>>>(x, xb, 1048576);
  cvt_f32_bf16<<<3072, 256, 0, stream>>>(qkv_w, wqkvb, 786432);
  cvt_f32_bf16<<<1024, 256, 0, stream>>>(out_w, woutb, 262144);

  gemm_bt<__hip_bfloat16><<<dim3(24, 32), 256, 0, stream>>>(xb, wqkvb, qkvb, 4096, 3072, 1024);

  rope_pack<<<dim3(32, 32), 256, 0, stream>>>(qkvb, Qb, Kb, VTb);

  // LDS-free: 16 q-slabs of 128 rows x 32 bh = 512 blocks, 4 waves each
  flash_attn<<<dim3(NBH, 16), 256, 0, stream>>>(Qb, Kb, VTb, yb);

  gemm_bt<float><<<dim3(8, 32), 256, 0, stream>>>(yb, woutb, out, 4096, 1024, 1024);
}

// Round 9
// 135.283 us; speedup vs baseline: 1.2791x; 1.2791x over previous
//
#include <hip/hip_runtime.h>
#include <hip/hip_bf16.h>
#include <cstdint>
#include <cstddef>

#define B_SZ   2
#define T_CTX  2048
#define DIM_C  1024
#define NHEAD  16
#define HD     64
#define NBH    (B_SZ*NHEAD)

typedef __attribute__((ext_vector_type(8))) short short8;
typedef __attribute__((ext_vector_type(4))) float f32x4;
typedef __attribute__((ext_vector_type(16))) float f32x16;

union BV8 { short8 s; __hip_bfloat16 h[8]; unsigned short u[8]; };
union U32x4 { uint32_t u[4]; short8 s8; };

#define GLD16(gp, lp) \
  __builtin_amdgcn_global_load_lds((const __attribute__((address_space(1))) void*)(gp), \
                                   (__attribute__((address_space(3))) void*)(lp), 16, 0, 0)

// pack two f32 -> bf16 pair (lo = first arg), pure IR (hazard-safe feed into MFMA)
__device__ inline uint32_t pkbf(float a, float b) {
  union { __hip_bfloat16 h; unsigned short u; } ua, ub;
  ua.h = __float2bfloat16(a);
  ub.h = __float2bfloat16(b);
  return ((uint32_t)ub.u << 16) | (uint32_t)ua.u;
}

// ---------------- fp32 -> bf16 convert ----------------
__global__ __launch_bounds__(256) void cvt_f32_bf16(const float* __restrict__ in,
                                                    __hip_bfloat16* __restrict__ out,
                                                    int n4) {
  int i = blockIdx.x * 256 + threadIdx.x;
  if (i >= n4) return;
  float4 v = reinterpret_cast<const float4*>(in)[i];
  BV8 o;
  o.h[0] = __float2bfloat16(v.x);
  o.h[1] = __float2bfloat16(v.y);
  o.h[2] = __float2bfloat16(v.z);
  o.h[3] = __float2bfloat16(v.w);
  ushort4 st = { o.u[0], o.u[1], o.u[2], o.u[3] };
  reinterpret_cast<ushort4*>(out)[i] = st;
}

// ---------------- bf16 GEMM, C = A[M,K] * Bt[N,K]^T ----------------
template <typename OutT>
__global__ __launch_bounds__(256) void gemm_bt(const __hip_bfloat16* __restrict__ A,
                                               const __hip_bfloat16* __restrict__ Bt,
                                               OutT* __restrict__ C,
                                               int M, int N, int K) {
  __shared__ __align__(16) __hip_bfloat16 As[128 * 32];
  __shared__ __align__(16) __hip_bfloat16 Bs[128 * 32];
  const int tid = threadIdx.x;
  const int w = tid >> 6, l = tid & 63;
  const int l15 = l & 15, l4 = l >> 4;
  const int wr = w >> 1, wc = w & 1;
  const long bm = (long)blockIdx.y * 128;
  const long bn = (long)blockIdx.x * 128;

  f32x4 acc[4][4] = {};

  const int srow = tid >> 2;
  const int scol = (tid & 3) * 16;
  char* AsB = (char*)As;
  char* BsB = (char*)Bs;
  const char* Ab  = (const char*)A;
  const char* Btb = (const char*)Bt;

  for (int kt = 0; kt < K; kt += 32) {
    __syncthreads();
#pragma unroll
    for (int it = 0; it < 2; ++it) {
      long arow = bm + it * 64 + srow;
      GLD16(Ab + (arow * K + kt) * 2 + scol, AsB + it * 4096 + w * 1024);
      long brow = bn + it * 64 + srow;
      GLD16(Btb + (brow * K + kt) * 2 + scol, BsB + it * 4096 + w * 1024);
    }
    __syncthreads();
    short8 aF[4], bF[4];
#pragma unroll
    for (int m = 0; m < 4; ++m)
      aF[m] = *(const short8*)(AsB + (wr * 64 + m * 16 + l15) * 64 + l4 * 16);
#pragma unroll
    for (int n = 0; n < 4; ++n)
      bF[n] = *(const short8*)(BsB + (wc * 64 + n * 16 + l15) * 64 + l4 * 16);
#pragma unroll
    for (int m = 0; m < 4; ++m)
#pragma unroll
      for (int n = 0; n < 4; ++n)
        acc[m][n] = __builtin_amdgcn_mfma_f32_16x16x32_bf16(aF[m], bF[n], acc[m][n], 0, 0, 0);
  }

#pragma unroll
  for (int m = 0; m < 4; ++m)
#pragma unroll
    for (int n = 0; n < 4; ++n)
#pragma unroll
      for (int r = 0; r < 4; ++r) {
        long row = bm + wr * 64 + m * 16 + l4 * 4 + r;
        long col = bn + wc * 64 + n * 16 + l15;
        float v = acc[m][n][r];
        if constexpr (sizeof(OutT) == 2) {
          C[row * N + col] = __float2bfloat16(v);
        } else {
          C[row * N + col] = v;
        }
      }
}

// ---------------- RoPE + repack ----------------
// Q scale folds softmax 1/8 AND log2(e) so attention softmax can use exp2 natively.
__global__ __launch_bounds__(256) void rope_pack(const __hip_bfloat16* __restrict__ qkv,
                                                 __hip_bfloat16* __restrict__ Qb,
                                                 __hip_bfloat16* __restrict__ Kb,
                                                 __hip_bfloat16* __restrict__ VTb) {
  __shared__ __hip_bfloat16 vt[64][72];
  const int bh = blockIdx.x;
  const int b = bh >> 4, h = bh & 15;
  const int t0 = blockIdx.y * 64;
  const int tid = threadIdx.x;
  const float QSCL = 0.125f * 1.4426950408889634f;

#pragma unroll
  for (int rep = 0; rep < 2; ++rep) {
    int idx = rep * 256 + tid;
    int tt = idx >> 3;
    int d0 = (idx & 7) * 8;
    int t = t0 + tt;
    size_t src = ((size_t)(b * T_CTX + t)) * 3072 + h * 64 + d0;
    BV8 qv, kv, vv, qo, ko;
    qv.s = *(const short8*)(qkv + src);
    kv.s = *(const short8*)(qkv + src + 1024);
    vv.s = *(const short8*)(qkv + src + 2048);
#pragma unroll
    for (int p = 0; p < 4; ++p) {
      int i = (d0 >> 1) + p;
      float inv = exp2f(-13.287712379549449f * ((float)(2 * i) * (1.0f / 64.0f)));
      float ang = (float)t * inv;
      float sn, cn;
      sincosf(ang, &sn, &cn);
      float q1 = __bfloat162float(qv.h[2 * p]);
      float q2 = __bfloat162float(qv.h[2 * p + 1]);
      float k1 = __bfloat162float(kv.h[2 * p]);
      float k2 = __bfloat162float(kv.h[2 * p + 1]);
      qo.h[2 * p]     = __float2bfloat16((q1 * cn - q2 * sn) * QSCL);
      qo.h[2 * p + 1] = __float2bfloat16((q1 * sn + q2 * cn) * QSCL);
      ko.h[2 * p]     = __float2bfloat16(k1 * cn - k2 * sn);
      ko.h[2 * p + 1] = __float2bfloat16(k1 * sn + k2 * cn);
    }
    size_t dst = ((size_t)bh * T_CTX + t) * 64 + d0;
    *(short8*)(Qb + dst) = qo.s;
    *(short8*)(Kb + dst) = ko.s;
#pragma unroll
    for (int j = 0; j < 8; ++j) vt[d0 + j][tt] = vv.h[j];
  }
  __syncthreads();
#pragma unroll
  for (int rep = 0; rep < 2; ++rep) {
    int idx = rep * 256 + tid;
    int d = idx >> 3;
    int toff = (idx & 7) * 8;
    BV8 o;
#pragma unroll
    for (int j = 0; j < 8; ++j) o.h[j] = vt[d][toff + j];
    *(short8*)(VTb + ((size_t)bh * 64 + d) * T_CTX + t0 + toff) = o.s;
  }
}

// ---------------- flash attention (causal), 32x32 MFMA, K-SPLIT ACROSS WAVES ----------------
// 2 waves per block; each wave covers ALL 64 q rows of the slab but only ITS 32-k half
// of each KV tile -> per-tile LDS fragment reads halve (8KB/wave vs 16KB). Fixed-base
// exp2 softmax has no cross-k dependency, so each wave accumulates partial O and l;
// one LDS merge at the epilogue (owned d-half exchange). Staging identical to round 7.
__global__ __launch_bounds__(128) void flash_attn(const __hip_bfloat16* __restrict__ Qb,
                                                  const __hip_bfloat16* __restrict__ Kb,
                                                  const __hip_bfloat16* __restrict__ VTb,
                                                  __hip_bfloat16* __restrict__ Y) {
  __shared__ __align__(16) char smem[32768];  // 2 bufs x (K 8KB + V 8KB); reused for merge
  const int bh = blockIdx.x;
  const int b = bh >> 4, h = bh & 15;
  const int qi = 31 - (int)blockIdx.y;  // longest first
  const int q0 = qi * 64;
  const int tid = threadIdx.x;
  const int w = tid >> 6, l = tid & 63;
  const int l31 = l & 31, hh = l >> 5;
  const int sw7 = (l31 & 7) << 4;

  // Q as B-operand, both qtiles: lane q = q0 + qt*32 + l31, d = dblk*16 + hh*8 + j
  short8 qB[2][4];
#pragma unroll
  for (int qt = 0; qt < 2; ++qt)
#pragma unroll
    for (int dblk = 0; dblk < 4; ++dblk)
      qB[qt][dblk] = *(const short8*)(Qb + ((size_t)bh * T_CTX + q0 + qt * 32 + l31) * 64 +
                                     dblk * 16 + hh * 8);

  // partial O^T per (dt, qtile): d = dt*32 + (r&3)+8*(r>>2)+4*hh, q = qt*32 + l31
  f32x16 o00 = {}, o01 = {}, o10 = {}, o11 = {};  // o{dt}{qt}
  float lrow0 = 0.0f, lrow1 = 0.0f;

  const int rowb = w * 8 + (l >> 3);  // 0..15
  const int colS = (l & 7) * 16;

#define STAGE(kv, bufsel)                                                              \
  {                                                                                    \
    const int kv0_ = (kv) << 6;                                                        \
    char* base_ = smem + (bufsel) * 16384;                                             \
    _Pragma("unroll")                                                                  \
    for (int rnd = 0; rnd < 4; ++rnd) {                                                \
      int row = rnd * 16 + rowb;                                                       \
      int sw = colS ^ ((row & 7) << 4);                                                \
      GLD16((const char*)Kb + (((size_t)bh * T_CTX + kv0_ + row) << 7) + sw,           \
            base_ + rnd * 2048 + w * 1024);                                            \
      GLD16((const char*)VTb + ((((size_t)bh * 64 + row) * T_CTX + kv0_) << 1) + sw,   \
            base_ + 8192 + rnd * 2048 + w * 1024);                                     \
    }                                                                                  \
  }

  STAGE(0, 0)

  int cur = 0;
  for (int t = 0; t <= qi; ++t) {
    const int kv0 = t << 6;
    __syncthreads();  // buf[cur] ready
    if (t < qi) STAGE(t + 1, cur ^ 1)
    const char* KsB = smem + cur * 16384;
    const char* VsB = KsB + 8192;

    // K fragments for THIS WAVE's k-half: rows w*32 + l31
    short8 kA[4];
#pragma unroll
    for (int dblk = 0; dblk < 4; ++dblk)
      kA[dblk] = *(const short8*)(KsB + (w * 32 + l31) * 128 + ((dblk * 32 + hh * 16) ^ sw7));
    // V^T fragments: rows d (both dt), cols = wave's k-half, 2 slices of 16
    short8 vA[2][2];
#pragma unroll
    for (int dt = 0; dt < 2; ++dt)
#pragma unroll
      for (int ks = 0; ks < 2; ++ks)
        vA[dt][ks] = *(const short8*)(VsB + (dt * 32 + l31) * 128 +
                                      ((w * 64 + ks * 32 + hh * 16) ^ sw7));

    const bool diag = (t == qi);
    const int kbase = kv0 + w * 32 + 4 * hh;

    auto qt_proc = [&](const short8* qBq, f32x16& od0, f32x16& od1, float& lrw, int qglob) {
      // QK^T: S^T block [32k(wave half) x 32q], k = kbase + (r&3)+8*(r>>2), q = qglob
      f32x16 sT = {};
#pragma unroll
      for (int dblk = 0; dblk < 4; ++dblk) {
        __builtin_amdgcn_s_setprio(1);
        sT = __builtin_amdgcn_mfma_f32_32x32x16_bf16(kA[dblk], qBq[dblk], sT, 0, 0, 0);
        __builtin_amdgcn_s_setprio(0);
      }
      if (diag) {
#pragma unroll
        for (int r = 0; r < 16; ++r) {
          int kg = kbase + (r & 3) + 8 * (r >> 2);
          sT[r] = (kg > qglob) ? -1e30f : sT[r];
        }
      }
      // fixed-base softmax: P = exp2(s); per-lane partial l
      float s8[8];
#pragma unroll
      for (int i = 0; i < 8; ++i) {
        sT[i]     = __builtin_amdgcn_exp2f(sT[i]);
        sT[i + 8] = __builtin_amdgcn_exp2f(sT[i + 8]);
        s8[i] = sT[i] + sT[i + 8];
      }
      float ps = ((s8[0] + s8[1]) + (s8[2] + s8[3])) + ((s8[4] + s8[5]) + (s8[6] + s8[7]));
      ps += __shfl_xor(ps, 32);  // merge hh halves (same q, other 16 k of wave half)
      lrw += ps;
      // P -> bf16 pairs
      uint32_t wk[8];
#pragma unroll
      for (int i = 0; i < 8; ++i) wk[i] = pkbf(sT[2 * i], sT[2 * i + 1]);
      // PV: 2 k-slices of 16 within the wave half
#pragma unroll
      for (int ks = 0; ks < 2; ++ks) {
        const int base = ks * 4;
        uint32_t own0 = wk[base + 0], own1 = wk[base + 1];
        uint32_t own2 = wk[base + 2], own3 = wk[base + 3];
        uint32_t e0 = (uint32_t)__shfl_xor((int)(hh ? own0 : own2), 32);
        uint32_t e1 = (uint32_t)__shfl_xor((int)(hh ? own1 : own3), 32);
        U32x4 u;
        u.u[0] = hh ? e0 : own0;
        u.u[1] = hh ? e1 : own1;
        u.u[2] = hh ? own2 : e0;
        u.u[3] = hh ? own3 : e1;
        __builtin_amdgcn_s_setprio(1);
        od0 = __builtin_amdgcn_mfma_f32_32x32x16_bf16(vA[0][ks], u.s8, od0, 0, 0, 0);
        od1 = __builtin_amdgcn_mfma_f32_32x32x16_bf16(vA[1][ks], u.s8, od1, 0, 0, 0);
        __builtin_amdgcn_s_setprio(0);
      }
    };

    qt_proc(qB[0], o00, o10, lrow0, q0 + l31);
    qt_proc(qB[1], o01, o11, lrow1, q0 + 32 + l31);

    cur ^= 1;
  }

  // ---- cross-wave merge: wave w owns d-half w (wave0: o0x, wave1: o1x) ----
  // LDS: region[w] = wave w's NON-owned partials, [2 qt][32 q][36 pad] f32; lr at 4608.
  __syncthreads();  // last tile's LDS reads done before overwrite
  {
    float* exch = (float*)smem;
    float* wreg = exch + w * 2304;
    float* lr = exch + 4608;
    const f32x16& n0 = w ? o00 : o10;  // qtile0 non-owned
    const f32x16& n1 = w ? o01 : o11;  // qtile1 non-owned
#pragma unroll
    for (int m = 0; m < 4; ++m) {
      f32x4 v0, v1;
#pragma unroll
      for (int i = 0; i < 4; ++i) { v0[i] = n0[m * 4 + i]; v1[i] = n1[m * 4 + i]; }
      *(f32x4*)(wreg + l31 * 36 + 8 * m + 4 * hh) = v0;
      *(f32x4*)(wreg + (32 + l31) * 36 + 8 * m + 4 * hh) = v1;
    }
    if (hh == 0) {
      lr[(w * 2 + 0) * 32 + l31] = lrow0;
      lr[(w * 2 + 1) * 32 + l31] = lrow1;
    }
    __syncthreads();
    float* oreg = exch + (1 - w) * 2304;
    float lt0 = lrow0 + lr[((1 - w) * 2 + 0) * 32 + l31];
    float lt1 = lrow1 + lr[((1 - w) * 2 + 1) * 32 + l31];
    f32x16& own0 = w ? o10 : o00;
    f32x16& own1 = w ? o11 : o01;
#pragma unroll
    for (int m = 0; m < 4; ++m) {
      f32x4 a0 = *(const f32x4*)(oreg + l31 * 36 + 8 * m + 4 * hh);
      f32x4 a1 = *(const f32x4*)(oreg + (32 + l31) * 36 + 8 * m + 4 * hh);
#pragma unroll
      for (int i = 0; i < 4; ++i) { own0[m * 4 + i] += a0[i]; own1[m * 4 + i] += a1[i]; }
    }
    // write Y: wave's owned 32 d-cols, both qtiles
    float inv0 = 1.0f / lt0;
    float inv1 = 1.0f / lt1;
#pragma unroll
    for (int qt = 0; qt < 2; ++qt) {
      const f32x16& ov = qt ? own1 : own0;
      float inv = qt ? inv1 : inv0;
      size_t rowoff = ((size_t)(b * T_CTX + q0 + qt * 32 + l31)) * DIM_C + h * 64 + w * 32;
#pragma unroll
      for (int m = 0; m < 4; ++m) {
        union { ushort4 v; unsigned short us[4]; } st;
#pragma unroll
        for (int i = 0; i < 4; ++i) {
          union { __hip_bfloat16 h2; unsigned short u; } cv;
          cv.h2 = __float2bfloat16(ov[m * 4 + i] * inv);
          st.us[i] = cv.u;
        }
        *(ushort4*)(Y + rowoff + 8 * m + 4 * hh) = st.v;
      }
    }
  }
#undef STAGE
}

// ---------------- launcher ----------------
extern "C" void kernel_launch(void* const* d_in, const int* in_sizes, int n_in,
                              void* d_out, int out_size, void* d_ws, size_t ws_size,
                              hipStream_t stream) {
  const float* x     = (const float*)d_in[0];
  const float* qkv_w = (const float*)d_in[1];
  const float* out_w = (const float*)d_in[2];
  float* out = (float*)d_out;

  char* ws = (char*)d_ws;
  const size_t MB = 1024 * 1024;
  __hip_bfloat16* xb    = (__hip_bfloat16*)(ws + 0 * MB);
  __hip_bfloat16* wqkvb = (__hip_bfloat16*)(ws + 8 * MB);
  __hip_bfloat16* woutb = (__hip_bfloat16*)(ws + 14 * MB);
  __hip_bfloat16* qkvb  = (__hip_bfloat16*)(ws + 16 * MB);
  __hip_bfloat16* Qb    = (__hip_bfloat16*)(ws + 40 * MB);
  __hip_bfloat16* Kb    = (__hip_bfloat16*)(ws + 48 * MB);
  __hip_bfloat16* VTb   = (__hip_bfloat16*)(ws + 56 * MB);
  __hip_bfloat16* yb    = (__hip_bfloat16*)(ws + 64 * MB);

  cvt_f32_bf16<<<4096, 256, 0, stream>>>(x, xb, 1048576);
  cvt_f32_bf16<<<3072, 256, 0, stream>>>(qkv_w, wqkvb, 786432);
  cvt_f32_bf16<<<1024, 256, 0, stream>>>(out_w, woutb, 262144);

  gemm_bt<__hip_bfloat16><<<dim3(24, 32), 256, 0, stream>>>(xb, wqkvb, qkvb, 4096, 3072, 1024);

  rope_pack<<<dim3(32, 32), 256, 0, stream>>>(qkvb, Qb, Kb, VTb);

  // 32 q-slabs of 64 rows x 32 bh = 1024 blocks, 2 waves each (k-split within block)
  flash_attn<<<dim3(NBH, 32), 128, 0, stream>>>(Qb, Kb, VTb, yb);

  gemm_bt<float><<<dim3(8, 32), 256, 0, stream>>>(yb, woutb, out, 4096, 1024, 1024);
}

// Round 10
// 130.892 us; speedup vs baseline: 1.3220x; 1.0335x over previous
//
#include <hip/hip_runtime.h>
#include <hip/hip_bf16.h>
#include <cstdint>
#include <cstddef>

#define B_SZ   2
#define T_CTX  2048
#define DIM_C  1024
#define NHEAD  16
#define HD     64
#define NBH    (B_SZ*NHEAD)

typedef __attribute__((ext_vector_type(8))) short short8;
typedef __attribute__((ext_vector_type(4))) float f32x4;
typedef __attribute__((ext_vector_type(16))) float f32x16;

union BV8 { short8 s; __hip_bfloat16 h[8]; unsigned short u[8]; };
union U32x4 { uint32_t u[4]; short8 s8; };

#define GLD16(gp, lp) \
  __builtin_amdgcn_global_load_lds((const __attribute__((address_space(1))) void*)(gp), \
                                   (__attribute__((address_space(3))) void*)(lp), 16, 0, 0)

// pack two f32 -> bf16 pair (lo = first arg), pure IR (hazard-safe feed into MFMA)
__device__ inline uint32_t pkbf(float a, float b) {
  union { __hip_bfloat16 h; unsigned short u; } ua, ub;
  ua.h = __float2bfloat16(a);
  ub.h = __float2bfloat16(b);
  return ((uint32_t)ub.u << 16) | (uint32_t)ua.u;
}

// ---------------- fp32 -> bf16 convert ----------------
__global__ __launch_bounds__(256) void cvt_f32_bf16(const float* __restrict__ in,
                                                    __hip_bfloat16* __restrict__ out,
                                                    int n4) {
  int i = blockIdx.x * 256 + threadIdx.x;
  if (i >= n4) return;
  float4 v = reinterpret_cast<const float4*>(in)[i];
  BV8 o;
  o.h[0] = __float2bfloat16(v.x);
  o.h[1] = __float2bfloat16(v.y);
  o.h[2] = __float2bfloat16(v.z);
  o.h[3] = __float2bfloat16(v.w);
  ushort4 st = { o.u[0], o.u[1], o.u[2], o.u[3] };
  reinterpret_cast<ushort4*>(out)[i] = st;
}

// ---------------- bf16 GEMM, C = A[M,K] * Bt[N,K]^T ----------------
template <typename OutT>
__global__ __launch_bounds__(256) void gemm_bt(const __hip_bfloat16* __restrict__ A,
                                               const __hip_bfloat16* __restrict__ Bt,
                                               OutT* __restrict__ C,
                                               int M, int N, int K) {
  __shared__ __align__(16) __hip_bfloat16 As[128 * 32];
  __shared__ __align__(16) __hip_bfloat16 Bs[128 * 32];
  const int tid = threadIdx.x;
  const int w = tid >> 6, l = tid & 63;
  const int l15 = l & 15, l4 = l >> 4;
  const int wr = w >> 1, wc = w & 1;
  const long bm = (long)blockIdx.y * 128;
  const long bn = (long)blockIdx.x * 128;

  f32x4 acc[4][4] = {};

  const int srow = tid >> 2;
  const int scol = (tid & 3) * 16;
  char* AsB = (char*)As;
  char* BsB = (char*)Bs;
  const char* Ab  = (const char*)A;
  const char* Btb = (const char*)Bt;

  for (int kt = 0; kt < K; kt += 32) {
    __syncthreads();
#pragma unroll
    for (int it = 0; it < 2; ++it) {
      long arow = bm + it * 64 + srow;
      GLD16(Ab + (arow * K + kt) * 2 + scol, AsB + it * 4096 + w * 1024);
      long brow = bn + it * 64 + srow;
      GLD16(Btb + (brow * K + kt) * 2 + scol, BsB + it * 4096 + w * 1024);
    }
    __syncthreads();
    short8 aF[4], bF[4];
#pragma unroll
    for (int m = 0; m < 4; ++m)
      aF[m] = *(const short8*)(AsB + (wr * 64 + m * 16 + l15) * 64 + l4 * 16);
#pragma unroll
    for (int n = 0; n < 4; ++n)
      bF[n] = *(const short8*)(BsB + (wc * 64 + n * 16 + l15) * 64 + l4 * 16);
#pragma unroll
    for (int m = 0; m < 4; ++m)
#pragma unroll
      for (int n = 0; n < 4; ++n)
        acc[m][n] = __builtin_amdgcn_mfma_f32_16x16x32_bf16(aF[m], bF[n], acc[m][n], 0, 0, 0);
  }

#pragma unroll
  for (int m = 0; m < 4; ++m)
#pragma unroll
    for (int n = 0; n < 4; ++n)
#pragma unroll
      for (int r = 0; r < 4; ++r) {
        long row = bm + wr * 64 + m * 16 + l4 * 4 + r;
        long col = bn + wc * 64 + n * 16 + l15;
        float v = acc[m][n][r];
        if constexpr (sizeof(OutT) == 2) {
          C[row * N + col] = __float2bfloat16(v);
        } else {
          C[row * N + col] = v;
        }
      }
}

// ---------------- RoPE + repack ----------------
// Q scale folds softmax 1/8 AND log2(e) so attention softmax can use exp2 natively.
__global__ __launch_bounds__(256) void rope_pack(const __hip_bfloat16* __restrict__ qkv,
                                                 __hip_bfloat16* __restrict__ Qb,
                                                 __hip_bfloat16* __restrict__ Kb,
                                                 __hip_bfloat16* __restrict__ VTb) {
  __shared__ __hip_bfloat16 vt[64][72];
  const int bh = blockIdx.x;
  const int b = bh >> 4, h = bh & 15;
  const int t0 = blockIdx.y * 64;
  const int tid = threadIdx.x;
  const float QSCL = 0.125f * 1.4426950408889634f;

#pragma unroll
  for (int rep = 0; rep < 2; ++rep) {
    int idx = rep * 256 + tid;
    int tt = idx >> 3;
    int d0 = (idx & 7) * 8;
    int t = t0 + tt;
    size_t src = ((size_t)(b * T_CTX + t)) * 3072 + h * 64 + d0;
    BV8 qv, kv, vv, qo, ko;
    qv.s = *(const short8*)(qkv + src);
    kv.s = *(const short8*)(qkv + src + 1024);
    vv.s = *(const short8*)(qkv + src + 2048);
#pragma unroll
    for (int p = 0; p < 4; ++p) {
      int i = (d0 >> 1) + p;
      float inv = exp2f(-13.287712379549449f * ((float)(2 * i) * (1.0f / 64.0f)));
      float ang = (float)t * inv;
      float sn, cn;
      sincosf(ang, &sn, &cn);
      float q1 = __bfloat162float(qv.h[2 * p]);
      float q2 = __bfloat162float(qv.h[2 * p + 1]);
      float k1 = __bfloat162float(kv.h[2 * p]);
      float k2 = __bfloat162float(kv.h[2 * p + 1]);
      qo.h[2 * p]     = __float2bfloat16((q1 * cn - q2 * sn) * QSCL);
      qo.h[2 * p + 1] = __float2bfloat16((q1 * sn + q2 * cn) * QSCL);
      ko.h[2 * p]     = __float2bfloat16(k1 * cn - k2 * sn);
      ko.h[2 * p + 1] = __float2bfloat16(k1 * sn + k2 * cn);
    }
    size_t dst = ((size_t)bh * T_CTX + t) * 64 + d0;
    *(short8*)(Qb + dst) = qo.s;
    *(short8*)(Kb + dst) = ko.s;
#pragma unroll
    for (int j = 0; j < 8; ++j) vt[d0 + j][tt] = vv.h[j];
  }
  __syncthreads();
#pragma unroll
  for (int rep = 0; rep < 2; ++rep) {
    int idx = rep * 256 + tid;
    int d = idx >> 3;
    int toff = (idx & 7) * 8;
    BV8 o;
#pragma unroll
    for (int j = 0; j < 8; ++j) o.h[j] = vt[d][toff + j];
    *(short8*)(VTb + ((size_t)bh * 64 + d) * T_CTX + t0 + toff) = o.s;
  }
}

// ---------------- flash attention (causal), 32x32 MFMA, BALANCED slab pairs ----------------
// 64 slabs of 32 q-rows; block y runs slab 63-y (long) then slab y (short):
// exactly 33 KV tiles per block -> 1024 uniform blocks x 2 waves = sustained 2 waves/SIMD.
// Per tile: 2 waves k-split (each 32q x 32k, fixed-base exp2 softmax, partial O/l).
// Buffer parity carried across the phase boundary by global round counter rr.
// Single cross-wave merge at the END (both slabs) reusing staging LDS (no race with prefetch).
__global__ __launch_bounds__(128) void flash_attn(const __hip_bfloat16* __restrict__ Qb,
                                                  const __hip_bfloat16* __restrict__ Kb,
                                                  const __hip_bfloat16* __restrict__ VTb,
                                                  __hip_bfloat16* __restrict__ Y) {
  __shared__ __align__(16) char smem[32768];  // 2 bufs x (K 8KB + V 8KB); reused for merge
  const int bh = blockIdx.x;
  const int b = bh >> 4, h = bh & 15;
  const int y = blockIdx.y;
  const int jA = 63 - y;            // long slab (q [32*jA, 32*jA+32))
  const int jB = y;                 // short slab
  const int tmaxA = jA >> 1;        // tiles-1 for slab A (KVBLK=64)
  const int tmaxB = jB >> 1;
  const int q0A = jA << 5, q0B = jB << 5;
  const int tid = threadIdx.x;
  const int w = tid >> 6, l = tid & 63;
  const int l31 = l & 31, hh = l >> 5;
  const int sw7 = (l31 & 7) << 4;
  const int rowb = w * 8 + (l >> 3);  // 0..15
  const int colS = (l & 7) * 16;

#define STAGE(kv, bufsel)                                                              \
  {                                                                                    \
    const int kv0_ = (kv) << 6;                                                        \
    char* base_ = smem + (bufsel) * 16384;                                             \
    _Pragma("unroll")                                                                  \
    for (int rnd = 0; rnd < 4; ++rnd) {                                                \
      int row = rnd * 16 + rowb;                                                       \
      int sw = colS ^ ((row & 7) << 4);                                                \
      GLD16((const char*)Kb + (((size_t)bh * T_CTX + kv0_ + row) << 7) + sw,           \
            base_ + rnd * 2048 + w * 1024);                                            \
      GLD16((const char*)VTb + ((((size_t)bh * 64 + row) * T_CTX + kv0_) << 1) + sw,   \
            base_ + 8192 + rnd * 2048 + w * 1024);                                     \
    }                                                                                  \
  }

  // partial O^T per (slab, dt): d = dt*32 + (r&3)+8*(r>>2)+4*hh, q = q0 + l31
  f32x16 oA0 = {}, oA1 = {}, oB0 = {}, oB1 = {};
  float lrA = 0.0f, lrB = 0.0f;

  STAGE(0, 0)

  int rr = 0;  // global round counter 0..32
#pragma unroll
  for (int ph = 0; ph < 2; ++ph) {
    const int q0 = ph ? q0B : q0A;
    const int tmax = ph ? tmaxB : tmaxA;
    const int qglob = q0 + l31;
    f32x16& od0 = ph ? oB0 : oA0;
    f32x16& od1 = ph ? oB1 : oA1;
    float& lrw = ph ? lrB : lrA;

    // Q as B-operand: lane q = qglob, contraction d = dblk*16 + hh*8 + j
    short8 qB[4];
#pragma unroll
    for (int dblk = 0; dblk < 4; ++dblk)
      qB[dblk] = *(const short8*)(Qb + ((size_t)bh * T_CTX + qglob) * 64 + dblk * 16 + hh * 8);

    for (int t = 0; t <= tmax; ++t, ++rr) {
      __syncthreads();  // buf[rr&1] ready
      if (rr < 32) {
        const int nseq = (rr + 1 <= tmaxA) ? rr + 1 : rr - tmaxA;  // wrap to slab B
        STAGE(nseq, (rr + 1) & 1)
      }
      const char* KsB = smem + (rr & 1) * 16384;
      const char* VsB = KsB + 8192;
      const int kv0 = t << 6;

      // K fragments for this wave's k-half: rows w*32 + l31
      short8 kA[4];
#pragma unroll
      for (int dblk = 0; dblk < 4; ++dblk)
        kA[dblk] = *(const short8*)(KsB + (w * 32 + l31) * 128 + ((dblk * 32 + hh * 16) ^ sw7));
      // V^T fragments: rows d (both dt), cols = wave's k-half, 2 slices of 16
      short8 vA[2][2];
#pragma unroll
      for (int dt = 0; dt < 2; ++dt)
#pragma unroll
        for (int ks = 0; ks < 2; ++ks)
          vA[dt][ks] = *(const short8*)(VsB + (dt * 32 + l31) * 128 +
                                        ((w * 64 + ks * 32 + hh * 16) ^ sw7));

      // QK^T: k = kbase + (r&3)+8*(r>>2), q = qglob
      f32x16 sT = {};
#pragma unroll
      for (int dblk = 0; dblk < 4; ++dblk) {
        __builtin_amdgcn_s_setprio(1);
        sT = __builtin_amdgcn_mfma_f32_32x32x16_bf16(kA[dblk], qB[dblk], sT, 0, 0, 0);
        __builtin_amdgcn_s_setprio(0);
      }
      if (t == tmax) {  // diagonal tile: causal mask
        const int kbase = kv0 + w * 32 + 4 * hh;
#pragma unroll
        for (int r = 0; r < 16; ++r) {
          int kg = kbase + (r & 3) + 8 * (r >> 2);
          sT[r] = (kg > qglob) ? -1e30f : sT[r];
        }
      }
      // fixed-base softmax: P = exp2(s); per-lane partial l
      float s8[8];
#pragma unroll
      for (int i = 0; i < 8; ++i) {
        sT[i]     = __builtin_amdgcn_exp2f(sT[i]);
        sT[i + 8] = __builtin_amdgcn_exp2f(sT[i + 8]);
        s8[i] = sT[i] + sT[i + 8];
      }
      float ps = ((s8[0] + s8[1]) + (s8[2] + s8[3])) + ((s8[4] + s8[5]) + (s8[6] + s8[7]));
      ps += __shfl_xor(ps, 32);  // merge hh halves (same q)
      lrw += ps;
      // P -> bf16 pairs
      uint32_t wk[8];
#pragma unroll
      for (int i = 0; i < 8; ++i) wk[i] = pkbf(sT[2 * i], sT[2 * i + 1]);
      // PV: 2 k-slices of 16 within the wave half
#pragma unroll
      for (int ks = 0; ks < 2; ++ks) {
        const int base = ks * 4;
        uint32_t own0 = wk[base + 0], own1 = wk[base + 1];
        uint32_t own2 = wk[base + 2], own3 = wk[base + 3];
        uint32_t e0 = (uint32_t)__shfl_xor((int)(hh ? own0 : own2), 32);
        uint32_t e1 = (uint32_t)__shfl_xor((int)(hh ? own1 : own3), 32);
        U32x4 u;
        u.u[0] = hh ? e0 : own0;
        u.u[1] = hh ? e1 : own1;
        u.u[2] = hh ? own2 : e0;
        u.u[3] = hh ? own3 : e1;
        __builtin_amdgcn_s_setprio(1);
        od0 = __builtin_amdgcn_mfma_f32_32x32x16_bf16(vA[0][ks], u.s8, od0, 0, 0, 0);
        od1 = __builtin_amdgcn_mfma_f32_32x32x16_bf16(vA[1][ks], u.s8, od1, 0, 0, 0);
        __builtin_amdgcn_s_setprio(0);
      }
    }
  }

  // ---- cross-wave merge (both slabs): wave w owns d-half w ----
  __syncthreads();  // all staging + LDS reads done; smem free for exchange
  {
    float* exch = (float*)smem;          // [2 wave][2 slab][32 q][36 pad] f32 = 18432B
    float* wreg = exch + w * 2304;
    float* lr = exch + 4608;             // [2 wave][2 slab][32] f32 at byte 18432
    const f32x16& nA = w ? oA0 : oA1;    // non-owned d-half, slab A
    const f32x16& nB = w ? oB0 : oB1;
#pragma unroll
    for (int m = 0; m < 4; ++m) {
      f32x4 va, vb;
#pragma unroll
      for (int i = 0; i < 4; ++i) { va[i] = nA[m * 4 + i]; vb[i] = nB[m * 4 + i]; }
      *(f32x4*)(wreg + l31 * 36 + 8 * m + 4 * hh) = va;
      *(f32x4*)(wreg + 1152 + l31 * 36 + 8 * m + 4 * hh) = vb;
    }
    if (hh == 0) {
      lr[(w * 2 + 0) * 32 + l31] = lrA;
      lr[(w * 2 + 1) * 32 + l31] = lrB;
    }
    __syncthreads();
    float* oreg = exch + (1 - w) * 2304;
    float ltA = lrA + lr[((1 - w) * 2 + 0) * 32 + l31];
    float ltB = lrB + lr[((1 - w) * 2 + 1) * 32 + l31];
    f32x16& ownA = w ? oA1 : oA0;
    f32x16& ownB = w ? oB1 : oB0;
#pragma unroll
    for (int m = 0; m < 4; ++m) {
      f32x4 aA = *(const f32x4*)(oreg + l31 * 36 + 8 * m + 4 * hh);
      f32x4 aB = *(const f32x4*)(oreg + 1152 + l31 * 36 + 8 * m + 4 * hh);
#pragma unroll
      for (int i = 0; i < 4; ++i) { ownA[m * 4 + i] += aA[i]; ownB[m * 4 + i] += aB[i]; }
    }
    // write Y: wave's owned 32 d-cols, both slabs
#pragma unroll
    for (int sl = 0; sl < 2; ++sl) {
      const f32x16& ov = sl ? ownB : ownA;
      float inv = 1.0f / (sl ? ltB : ltA);
      int q0s = sl ? q0B : q0A;
      size_t rowoff = ((size_t)(b * T_CTX + q0s + l31)) * DIM_C + h * 64 + w * 32;
#pragma unroll
      for (int m = 0; m < 4; ++m) {
        union { ushort4 v; unsigned short us[4]; } st;
#pragma unroll
        for (int i = 0; i < 4; ++i) {
          union { __hip_bfloat16 h2; unsigned short u; } cv;
          cv.h2 = __float2bfloat16(ov[m * 4 + i] * inv);
          st.us[i] = cv.u;
        }
        *(ushort4*)(Y + rowoff + 8 * m + 4 * hh) = st.v;
      }
    }
  }
#undef STAGE
}

// ---------------- launcher ----------------
extern "C" void kernel_launch(void* const* d_in, const int* in_sizes, int n_in,
                              void* d_out, int out_size, void* d_ws, size_t ws_size,
                              hipStream_t stream) {
  const float* x     = (const float*)d_in[0];
  const float* qkv_w = (const float*)d_in[1];
  const float* out_w = (const float*)d_in[2];
  float* out = (float*)d_out;

  char* ws = (char*)d_ws;
  const size_t MB = 1024 * 1024;
  __hip_bfloat16* xb    = (__hip_bfloat16*)(ws + 0 * MB);
  __hip_bfloat16* wqkvb = (__hip_bfloat16*)(ws + 8 * MB);
  __hip_bfloat16* woutb = (__hip_bfloat16*)(ws + 14 * MB);
  __hip_bfloat16* qkvb  = (__hip_bfloat16*)(ws + 16 * MB);
  __hip_bfloat16* Qb    = (__hip_bfloat16*)(ws + 40 * MB);
  __hip_bfloat16* Kb    = (__hip_bfloat16*)(ws + 48 * MB);
  __hip_bfloat16* VTb   = (__hip_bfloat16*)(ws + 56 * MB);
  __hip_bfloat16* yb    = (__hip_bfloat16*)(ws + 64 * MB);

  cvt_f32_bf16<<<4096, 256, 0, stream>>>(x, xb, 1048576);
  cvt_f32_bf16<<<3072, 256, 0, stream>>>(qkv_w, wqkvb, 786432);
  cvt_f32_bf16<<<1024, 256, 0, stream>>>(out_w, woutb, 262144);

  gemm_bt<__hip_bfloat16><<<dim3(24, 32), 256, 0, stream>>>(xb, wqkvb, qkvb, 4096, 3072, 1024);

  rope_pack<<<dim3(32, 32), 256, 0, stream>>>(qkvb, Qb, Kb, VTb);

  // balanced: 32 slab-pairs (63-y, y) x 32 bh = 1024 uniform blocks, 2 waves each
  flash_attn<<<dim3(NBH, 32), 128, 0, stream>>>(Qb, Kb, VTb, yb);

  gemm_bt<float><<<dim3(8, 32), 256, 0, stream>>>(yb, woutb, out, 4096, 1024, 1024);
}

// Round 11
// 127.054 us; speedup vs baseline: 1.3620x; 1.0302x over previous
//
#include <hip/hip_runtime.h>
#include <hip/hip_bf16.h>
#include <cstdint>
#include <cstddef>

#define B_SZ   2
#define T_CTX  2048
#define DIM_C  1024
#define NHEAD  16
#define HD     64
#define NBH    (B_SZ*NHEAD)

typedef __attribute__((ext_vector_type(8))) short short8;
typedef __attribute__((ext_vector_type(4))) float f32x4;
typedef __attribute__((ext_vector_type(16))) float f32x16;

union BV8 { short8 s; __hip_bfloat16 h[8]; unsigned short u[8]; };
union U32x4 { uint32_t u[4]; short8 s8; };

#define GLD16(gp, lp) \
  __builtin_amdgcn_global_load_lds((const __attribute__((address_space(1))) void*)(gp), \
                                   (__attribute__((address_space(3))) void*)(lp), 16, 0, 0)

// pack two f32 -> bf16 pair (lo = first arg), pure IR (hazard-safe feed into MFMA)
__device__ inline uint32_t pkbf(float a, float b) {
  union { __hip_bfloat16 h; unsigned short u; } ua, ub;
  ua.h = __float2bfloat16(a);
  ub.h = __float2bfloat16(b);
  return ((uint32_t)ub.u << 16) | (uint32_t)ua.u;
}

// ---------------- fp32 -> bf16 convert ----------------
__global__ __launch_bounds__(256) void cvt_f32_bf16(const float* __restrict__ in,
                                                    __hip_bfloat16* __restrict__ out,
                                                    int n4) {
  int i = blockIdx.x * 256 + threadIdx.x;
  if (i >= n4) return;
  float4 v = reinterpret_cast<const float4*>(in)[i];
  BV8 o;
  o.h[0] = __float2bfloat16(v.x);
  o.h[1] = __float2bfloat16(v.y);
  o.h[2] = __float2bfloat16(v.z);
  o.h[3] = __float2bfloat16(v.w);
  ushort4 st = { o.u[0], o.u[1], o.u[2], o.u[3] };
  reinterpret_cast<ushort4*>(out)[i] = st;
}

// ---------------- bf16 GEMM, C = A[M,K] * Bt[N,K]^T ----------------
template <typename OutT>
__global__ __launch_bounds__(256) void gemm_bt(const __hip_bfloat16* __restrict__ A,
                                               const __hip_bfloat16* __restrict__ Bt,
                                               OutT* __restrict__ C,
                                               int M, int N, int K) {
  __shared__ __align__(16) __hip_bfloat16 As[128 * 32];
  __shared__ __align__(16) __hip_bfloat16 Bs[128 * 32];
  const int tid = threadIdx.x;
  const int w = tid >> 6, l = tid & 63;
  const int l15 = l & 15, l4 = l >> 4;
  const int wr = w >> 1, wc = w & 1;
  const long bm = (long)blockIdx.y * 128;
  const long bn = (long)blockIdx.x * 128;

  f32x4 acc[4][4] = {};

  const int srow = tid >> 2;
  const int scol = (tid & 3) * 16;
  char* AsB = (char*)As;
  char* BsB = (char*)Bs;
  const char* Ab  = (const char*)A;
  const char* Btb = (const char*)Bt;

  for (int kt = 0; kt < K; kt += 32) {
    __syncthreads();
#pragma unroll
    for (int it = 0; it < 2; ++it) {
      long arow = bm + it * 64 + srow;
      GLD16(Ab + (arow * K + kt) * 2 + scol, AsB + it * 4096 + w * 1024);
      long brow = bn + it * 64 + srow;
      GLD16(Btb + (brow * K + kt) * 2 + scol, BsB + it * 4096 + w * 1024);
    }
    __syncthreads();
    short8 aF[4], bF[4];
#pragma unroll
    for (int m = 0; m < 4; ++m)
      aF[m] = *(const short8*)(AsB + (wr * 64 + m * 16 + l15) * 64 + l4 * 16);
#pragma unroll
    for (int n = 0; n < 4; ++n)
      bF[n] = *(const short8*)(BsB + (wc * 64 + n * 16 + l15) * 64 + l4 * 16);
#pragma unroll
    for (int m = 0; m < 4; ++m)
#pragma unroll
      for (int n = 0; n < 4; ++n)
        acc[m][n] = __builtin_amdgcn_mfma_f32_16x16x32_bf16(aF[m], bF[n], acc[m][n], 0, 0, 0);
  }

#pragma unroll
  for (int m = 0; m < 4; ++m)
#pragma unroll
    for (int n = 0; n < 4; ++n)
#pragma unroll
      for (int r = 0; r < 4; ++r) {
        long row = bm + wr * 64 + m * 16 + l4 * 4 + r;
        long col = bn + wc * 64 + n * 16 + l15;
        float v = acc[m][n][r];
        if constexpr (sizeof(OutT) == 2) {
          C[row * N + col] = __float2bfloat16(v);
        } else {
          C[row * N + col] = v;
        }
      }
}

// ---------------- RoPE + repack ----------------
// Q scale folds softmax 1/8 AND log2(e) so attention softmax can use exp2 natively.
__global__ __launch_bounds__(256) void rope_pack(const __hip_bfloat16* __restrict__ qkv,
                                                 __hip_bfloat16* __restrict__ Qb,
                                                 __hip_bfloat16* __restrict__ Kb,
                                                 __hip_bfloat16* __restrict__ VTb) {
  __shared__ __hip_bfloat16 vt[64][72];
  const int bh = blockIdx.x;
  const int b = bh >> 4, h = bh & 15;
  const int t0 = blockIdx.y * 64;
  const int tid = threadIdx.x;
  const float QSCL = 0.125f * 1.4426950408889634f;

#pragma unroll
  for (int rep = 0; rep < 2; ++rep) {
    int idx = rep * 256 + tid;
    int tt = idx >> 3;
    int d0 = (idx & 7) * 8;
    int t = t0 + tt;
    size_t src = ((size_t)(b * T_CTX + t)) * 3072 + h * 64 + d0;
    BV8 qv, kv, vv, qo, ko;
    qv.s = *(const short8*)(qkv + src);
    kv.s = *(const short8*)(qkv + src + 1024);
    vv.s = *(const short8*)(qkv + src + 2048);
#pragma unroll
    for (int p = 0; p < 4; ++p) {
      int i = (d0 >> 1) + p;
      float inv = exp2f(-13.287712379549449f * ((float)(2 * i) * (1.0f / 64.0f)));
      float ang = (float)t * inv;
      float sn, cn;
      sincosf(ang, &sn, &cn);
      float q1 = __bfloat162float(qv.h[2 * p]);
      float q2 = __bfloat162float(qv.h[2 * p + 1]);
      float k1 = __bfloat162float(kv.h[2 * p]);
      float k2 = __bfloat162float(kv.h[2 * p + 1]);
      qo.h[2 * p]     = __float2bfloat16((q1 * cn - q2 * sn) * QSCL);
      qo.h[2 * p + 1] = __float2bfloat16((q1 * sn + q2 * cn) * QSCL);
      ko.h[2 * p]     = __float2bfloat16(k1 * cn - k2 * sn);
      ko.h[2 * p + 1] = __float2bfloat16(k1 * sn + k2 * cn);
    }
    size_t dst = ((size_t)bh * T_CTX + t) * 64 + d0;
    *(short8*)(Qb + dst) = qo.s;
    *(short8*)(Kb + dst) = ko.s;
#pragma unroll
    for (int j = 0; j < 8; ++j) vt[d0 + j][tt] = vv.h[j];
  }
  __syncthreads();
#pragma unroll
  for (int rep = 0; rep < 2; ++rep) {
    int idx = rep * 256 + tid;
    int d = idx >> 3;
    int toff = (idx & 7) * 8;
    BV8 o;
#pragma unroll
    for (int j = 0; j < 8; ++j) o.h[j] = vt[d][toff + j];
    *(short8*)(VTb + ((size_t)bh * 64 + d) * T_CTX + t0 + toff) = o.s;
  }
}

// ---------------- flash attention (causal), 32x32 MFMA, 4-wave 64-row slabs ----------------
// 32 slabs of 64 q-rows; block y runs slab 31-y (long) then slab y (short): 33 tiles.
// 4 waves = (qsub, khalf): each wave 32q x 32k per tile -> staged tile amortized over
// 2x the q-rows of round 10 (halved L2 staging + staging VALU per CU).
// Fixed-base exp2 softmax (partials add; no rescale). End-of-kernel cross-wave merge:
// k-half partners exchange non-owned d-halves via XOR-swizzled f32 LDS (conflict-free).
__global__ __launch_bounds__(256) void flash_attn(const __hip_bfloat16* __restrict__ Qb,
                                                  const __hip_bfloat16* __restrict__ Kb,
                                                  const __hip_bfloat16* __restrict__ VTb,
                                                  __hip_bfloat16* __restrict__ Y) {
  __shared__ __align__(16) char smem[33792];  // 2x16KB staging; merge reuses 33KB
  const int bh = blockIdx.x;
  const int b = bh >> 4, h = bh & 15;
  const int y = blockIdx.y;
  const int jA = 31 - y;            // long slab (64 q-rows at jA*64), tiles jA+1
  const int jB = y;                 // short slab, tiles jB+1 (total 33)
  const int tid = threadIdx.x;
  const int w = tid >> 6, l = tid & 63;
  const int qsub = w >> 1, kh = w & 1;
  const int l31 = l & 31, hh = l >> 5;
  const int sw7 = (l31 & 7) << 4;
  const int rowb = tid >> 3;          // 0..31 (staging row within 32-row group)
  const int colS = (tid & 7) * 16;

#define STAGE(kv, bufsel)                                                              \
  {                                                                                    \
    const int kv0_ = (kv) << 6;                                                        \
    char* base_ = smem + (bufsel) * 16384;                                             \
    _Pragma("unroll")                                                                  \
    for (int rnd = 0; rnd < 2; ++rnd) {                                                \
      int row = rnd * 32 + rowb;                                                       \
      int sw = colS ^ ((row & 7) << 4);                                                \
      GLD16((const char*)Kb + (((size_t)bh * T_CTX + kv0_ + row) << 7) + sw,           \
            base_ + rnd * 4096 + w * 1024);                                            \
      GLD16((const char*)VTb + ((((size_t)bh * 64 + row) * T_CTX + kv0_) << 1) + sw,   \
            base_ + 8192 + rnd * 4096 + w * 1024);                                     \
    }                                                                                  \
  }

  // partial O^T per (slab, dt): d = dt*32 + (r&3)+8*(r>>2)+4*hh, q = slab_q0+qsub*32+l31
  f32x16 oA0 = {}, oA1 = {}, oB0 = {}, oB1 = {};
  float lrA = 0.0f, lrB = 0.0f;

  STAGE(0, 0)

  int rr = 0;  // global round counter 0..32 (buffer parity across phase boundary)
#pragma unroll
  for (int ph = 0; ph < 2; ++ph) {
    const int j = ph ? jB : jA;
    const int qglob = j * 64 + qsub * 32 + l31;
    f32x16& od0 = ph ? oB0 : oA0;
    f32x16& od1 = ph ? oB1 : oA1;
    float& lrw = ph ? lrB : lrA;

    // Q as B-operand: lane q = qglob, contraction d = dblk*16 + hh*8 + jj
    short8 qB[4];
#pragma unroll
    for (int dblk = 0; dblk < 4; ++dblk)
      qB[dblk] = *(const short8*)(Qb + ((size_t)bh * T_CTX + qglob) * 64 + dblk * 16 + hh * 8);

    for (int t = 0; t <= j; ++t, ++rr) {
      __syncthreads();  // buf[rr&1] ready
      if (rr < 32) {
        const int nseq = (rr + 1 <= jA) ? rr + 1 : rr - jA;  // wrap to slab B
        STAGE(nseq, (rr + 1) & 1)
      }
      const char* KsB = smem + (rr & 1) * 16384;
      const char* VsB = KsB + 8192;
      const int kv0 = t << 6;
      const bool lastT = (t == j);

      if (!(lastT && kh > qsub)) {  // skip fully-masked diag wave (uniform, no barriers)
        // K fragments for this wave's k-half: rows kh*32 + l31
        short8 kA[4];
#pragma unroll
        for (int dblk = 0; dblk < 4; ++dblk)
          kA[dblk] = *(const short8*)(KsB + (kh * 32 + l31) * 128 + ((dblk * 32 + hh * 16) ^ sw7));
        // V^T fragments: rows d (both dt), cols = wave's k-half, 2 slices of 16
        short8 vA[2][2];
#pragma unroll
        for (int dt = 0; dt < 2; ++dt)
#pragma unroll
          for (int ks = 0; ks < 2; ++ks)
            vA[dt][ks] = *(const short8*)(VsB + (dt * 32 + l31) * 128 +
                                          ((kh * 64 + ks * 32 + hh * 16) ^ sw7));

        // QK^T: k = kv0 + kh*32 + (r&3)+8*(r>>2)+4*hh, q = qglob
        f32x16 sT = {};
#pragma unroll
        for (int dblk = 0; dblk < 4; ++dblk) {
          __builtin_amdgcn_s_setprio(1);
          sT = __builtin_amdgcn_mfma_f32_32x32x16_bf16(kA[dblk], qB[dblk], sT, 0, 0, 0);
          __builtin_amdgcn_s_setprio(0);
        }
        if (lastT && kh == qsub) {  // diagonal 32x32 block: causal mask
          const int kbase = kv0 + kh * 32 + 4 * hh;
#pragma unroll
          for (int r = 0; r < 16; ++r) {
            int kg = kbase + (r & 3) + 8 * (r >> 2);
            sT[r] = (kg > qglob) ? -1e30f : sT[r];
          }
        }
        // fixed-base softmax: P = exp2(s); per-lane partial l
        float s8[8];
#pragma unroll
        for (int i = 0; i < 8; ++i) {
          sT[i]     = __builtin_amdgcn_exp2f(sT[i]);
          sT[i + 8] = __builtin_amdgcn_exp2f(sT[i + 8]);
          s8[i] = sT[i] + sT[i + 8];
        }
        float ps = ((s8[0] + s8[1]) + (s8[2] + s8[3])) + ((s8[4] + s8[5]) + (s8[6] + s8[7]));
        ps += __shfl_xor(ps, 32);  // merge hh halves (same q)
        lrw += ps;
        // P -> bf16 pairs
        uint32_t wk[8];
#pragma unroll
        for (int i = 0; i < 8; ++i) wk[i] = pkbf(sT[2 * i], sT[2 * i + 1]);
        // PV: 2 k-slices of 16 within the wave's k-half
#pragma unroll
        for (int ks = 0; ks < 2; ++ks) {
          const int base = ks * 4;
          uint32_t own0 = wk[base + 0], own1 = wk[base + 1];
          uint32_t own2 = wk[base + 2], own3 = wk[base + 3];
          uint32_t e0 = (uint32_t)__shfl_xor((int)(hh ? own0 : own2), 32);
          uint32_t e1 = (uint32_t)__shfl_xor((int)(hh ? own1 : own3), 32);
          U32x4 u;
          u.u[0] = hh ? e0 : own0;
          u.u[1] = hh ? e1 : own1;
          u.u[2] = hh ? own2 : e0;
          u.u[3] = hh ? own3 : e1;
          __builtin_amdgcn_s_setprio(1);
          od0 = __builtin_amdgcn_mfma_f32_32x32x16_bf16(vA[0][ks], u.s8, od0, 0, 0, 0);
          od1 = __builtin_amdgcn_mfma_f32_32x32x16_bf16(vA[1][ks], u.s8, od1, 0, 0, 0);
          __builtin_amdgcn_s_setprio(0);
        }
      }
    }
  }

  // ---- cross-wave merge: k-half partners (qsub, kh) <-> (qsub, kh^1); wave owns dt = kh ----
  __syncthreads();  // all staging + LDS reads done; smem free for exchange
  {
    float* exch = (float*)smem;   // 8 slots x 1024 f32 (32q x 32d, XOR-swizzled chunks)
    float* lst = exch + 8192;     // l partials: [slot][32]
    const int slotA = (0 * 2 + qsub) * 2 + kh;
    const int slotB = (1 * 2 + qsub) * 2 + kh;
    const f32x16& nA = kh ? oA0 : oA1;  // non-owned dt = 1-kh
    const f32x16& nB = kh ? oB0 : oB1;
#pragma unroll
    for (int m = 0; m < 4; ++m) {
      int c = ((2 * m + hh) ^ (l31 & 7)) * 4;
      f32x4 va, vb;
#pragma unroll
      for (int i = 0; i < 4; ++i) { va[i] = nA[m * 4 + i]; vb[i] = nB[m * 4 + i]; }
      *(f32x4*)(exch + slotA * 1024 + l31 * 32 + c) = va;
      *(f32x4*)(exch + slotB * 1024 + l31 * 32 + c) = vb;
    }
    if (hh == 0) {
      lst[slotA * 32 + l31] = lrA;
      lst[slotB * 32 + l31] = lrB;
    }
    __syncthreads();
    const int pA = (0 * 2 + qsub) * 2 + (kh ^ 1);
    const int pB = (1 * 2 + qsub) * 2 + (kh ^ 1);
    float ltA = lrA + lst[pA * 32 + l31];
    float ltB = lrB + lst[pB * 32 + l31];
    f32x16& ownA = kh ? oA1 : oA0;
    f32x16& ownB = kh ? oB1 : oB0;
#pragma unroll
    for (int m = 0; m < 4; ++m) {
      int c = ((2 * m + hh) ^ (l31 & 7)) * 4;
      f32x4 aA = *(const f32x4*)(exch + pA * 1024 + l31 * 32 + c);
      f32x4 aB = *(const f32x4*)(exch + pB * 1024 + l31 * 32 + c);
#pragma unroll
      for (int i = 0; i < 4; ++i) { ownA[m * 4 + i] += aA[i]; ownB[m * 4 + i] += aB[i]; }
    }
    // write Y: wave's owned 32 d-cols (kh half), both slabs
#pragma unroll
    for (int sl = 0; sl < 2; ++sl) {
      const f32x16& ov = sl ? ownB : ownA;
      float inv = 1.0f / (sl ? ltB : ltA);
      int q0s = (sl ? jB : jA) * 64 + qsub * 32;
      size_t rowoff = ((size_t)(b * T_CTX + q0s + l31)) * DIM_C + h * 64 + kh * 32;
#pragma unroll
      for (int m = 0; m < 4; ++m) {
        union { ushort4 v; unsigned short us[4]; } st;
#pragma unroll
        for (int i = 0; i < 4; ++i) {
          union { __hip_bfloat16 h2; unsigned short u; } cv;
          cv.h2 = __float2bfloat16(ov[m * 4 + i] * inv);
          st.us[i] = cv.u;
        }
        *(ushort4*)(Y + rowoff + 8 * m + 4 * hh) = st.v;
      }
    }
  }
#undef STAGE
}

// ---------------- launcher ----------------
extern "C" void kernel_launch(void* const* d_in, const int* in_sizes, int n_in,
                              void* d_out, int out_size, void* d_ws, size_t ws_size,
                              hipStream_t stream) {
  const float* x     = (const float*)d_in[0];
  const float* qkv_w = (const float*)d_in[1];
  const float* out_w = (const float*)d_in[2];
  float* out = (float*)d_out;

  char* ws = (char*)d_ws;
  const size_t MB = 1024 * 1024;
  __hip_bfloat16* xb    = (__hip_bfloat16*)(ws + 0 * MB);
  __hip_bfloat16* wqkvb = (__hip_bfloat16*)(ws + 8 * MB);
  __hip_bfloat16* woutb = (__hip_bfloat16*)(ws + 14 * MB);
  __hip_bfloat16* qkvb  = (__hip_bfloat16*)(ws + 16 * MB);
  __hip_bfloat16* Qb    = (__hip_bfloat16*)(ws + 40 * MB);
  __hip_bfloat16* Kb    = (__hip_bfloat16*)(ws + 48 * MB);
  __hip_bfloat16* VTb   = (__hip_bfloat16*)(ws + 56 * MB);
  __hip_bfloat16* yb    = (__hip_bfloat16*)(ws + 64 * MB);

  cvt_f32_bf16<<<4096, 256, 0, stream>>>(x, xb, 1048576);
  cvt_f32_bf16<<<3072, 256, 0, stream>>>(qkv_w, wqkvb, 786432);
  cvt_f32_bf16<<<1024, 256, 0, stream>>>(out_w, woutb, 262144);

  gemm_bt<__hip_bfloat16><<<dim3(24, 32), 256, 0, stream>>>(xb, wqkvb, qkvb, 4096, 3072, 1024);

  rope_pack<<<dim3(32, 32), 256, 0, stream>>>(qkvb, Qb, Kb, VTb);

  // 16 slab-pairs (31-y, y of 64-row slabs) x 32 bh = 512 blocks, 4 waves each
  flash_attn<<<dim3(NBH, 16), 256, 0, stream>>>(Qb, Kb, VTb, yb);

  gemm_bt<float><<<dim3(8, 32), 256, 0, stream>>>(yb, woutb, out, 4096, 1024, 1024);
}

// Round 12
// 126.136 us; speedup vs baseline: 1.3719x; 1.0073x over previous
//
#include <hip/hip_runtime.h>
#include <hip/hip_bf16.h>
#include <cstdint>
#include <cstddef>

#define B_SZ   2
#define T_CTX  2048
#define DIM_C  1024
#define NHEAD  16
#define HD     64
#define NBH    (B_SZ*NHEAD)

typedef __attribute__((ext_vector_type(8))) short short8;
typedef __attribute__((ext_vector_type(4))) float f32x4;
typedef __attribute__((ext_vector_type(16))) float f32x16;

union BV8 { short8 s; __hip_bfloat16 h[8]; unsigned short u[8]; };
union U32x4 { uint32_t u[4]; short8 s8; };

#define GLD16(gp, lp) \
  __builtin_amdgcn_global_load_lds((const __attribute__((address_space(1))) void*)(gp), \
                                   (__attribute__((address_space(3))) void*)(lp), 16, 0, 0)

// pack two f32 -> bf16 pair (lo = first arg), pure IR (hazard-safe feed into MFMA)
__device__ inline uint32_t pkbf(float a, float b) {
  union { __hip_bfloat16 h; unsigned short u; } ua, ub;
  ua.h = __float2bfloat16(a);
  ub.h = __float2bfloat16(b);
  return ((uint32_t)ub.u << 16) | (uint32_t)ua.u;
}

// ---------------- fp32 -> bf16 convert ----------------
__global__ __launch_bounds__(256) void cvt_f32_bf16(const float* __restrict__ in,
                                                    __hip_bfloat16* __restrict__ out,
                                                    int n4) {
  int i = blockIdx.x * 256 + threadIdx.x;
  if (i >= n4) return;
  float4 v = reinterpret_cast<const float4*>(in)[i];
  BV8 o;
  o.h[0] = __float2bfloat16(v.x);
  o.h[1] = __float2bfloat16(v.y);
  o.h[2] = __float2bfloat16(v.z);
  o.h[3] = __float2bfloat16(v.w);
  ushort4 st = { o.u[0], o.u[1], o.u[2], o.u[3] };
  reinterpret_cast<ushort4*>(out)[i] = st;
}

// ---------------- bf16 GEMM, C = A[M,K] * Bt[N,K]^T ----------------
template <typename OutT>
__global__ __launch_bounds__(256) void gemm_bt(const __hip_bfloat16* __restrict__ A,
                                               const __hip_bfloat16* __restrict__ Bt,
                                               OutT* __restrict__ C,
                                               int M, int N, int K) {
  __shared__ __align__(16) __hip_bfloat16 As[128 * 32];
  __shared__ __align__(16) __hip_bfloat16 Bs[128 * 32];
  const int tid = threadIdx.x;
  const int w = tid >> 6, l = tid & 63;
  const int l15 = l & 15, l4 = l >> 4;
  const int wr = w >> 1, wc = w & 1;
  const long bm = (long)blockIdx.y * 128;
  const long bn = (long)blockIdx.x * 128;

  f32x4 acc[4][4] = {};

  const int srow = tid >> 2;
  const int scol = (tid & 3) * 16;
  char* AsB = (char*)As;
  char* BsB = (char*)Bs;
  const char* Ab  = (const char*)A;
  const char* Btb = (const char*)Bt;

  for (int kt = 0; kt < K; kt += 32) {
    __syncthreads();
#pragma unroll
    for (int it = 0; it < 2; ++it) {
      long arow = bm + it * 64 + srow;
      GLD16(Ab + (arow * K + kt) * 2 + scol, AsB + it * 4096 + w * 1024);
      long brow = bn + it * 64 + srow;
      GLD16(Btb + (brow * K + kt) * 2 + scol, BsB + it * 4096 + w * 1024);
    }
    __syncthreads();
    short8 aF[4], bF[4];
#pragma unroll
    for (int m = 0; m < 4; ++m)
      aF[m] = *(const short8*)(AsB + (wr * 64 + m * 16 + l15) * 64 + l4 * 16);
#pragma unroll
    for (int n = 0; n < 4; ++n)
      bF[n] = *(const short8*)(BsB + (wc * 64 + n * 16 + l15) * 64 + l4 * 16);
#pragma unroll
    for (int m = 0; m < 4; ++m)
#pragma unroll
      for (int n = 0; n < 4; ++n)
        acc[m][n] = __builtin_amdgcn_mfma_f32_16x16x32_bf16(aF[m], bF[n], acc[m][n], 0, 0, 0);
  }

#pragma unroll
  for (int m = 0; m < 4; ++m)
#pragma unroll
    for (int n = 0; n < 4; ++n)
#pragma unroll
      for (int r = 0; r < 4; ++r) {
        long row = bm + wr * 64 + m * 16 + l4 * 4 + r;
        long col = bn + wc * 64 + n * 16 + l15;
        float v = acc[m][n][r];
        if constexpr (sizeof(OutT) == 2) {
          C[row * N + col] = __float2bfloat16(v);
        } else {
          C[row * N + col] = v;
        }
      }
}

// ---------------- RoPE + repack ----------------
// Q scale folds softmax 1/8 AND log2(e) so attention softmax can use exp2 natively.
__global__ __launch_bounds__(256) void rope_pack(const __hip_bfloat16* __restrict__ qkv,
                                                 __hip_bfloat16* __restrict__ Qb,
                                                 __hip_bfloat16* __restrict__ Kb,
                                                 __hip_bfloat16* __restrict__ VTb) {
  __shared__ __hip_bfloat16 vt[64][72];
  const int bh = blockIdx.x;
  const int b = bh >> 4, h = bh & 15;
  const int t0 = blockIdx.y * 64;
  const int tid = threadIdx.x;
  const float QSCL = 0.125f * 1.4426950408889634f;

#pragma unroll
  for (int rep = 0; rep < 2; ++rep) {
    int idx = rep * 256 + tid;
    int tt = idx >> 3;
    int d0 = (idx & 7) * 8;
    int t = t0 + tt;
    size_t src = ((size_t)(b * T_CTX + t)) * 3072 + h * 64 + d0;
    BV8 qv, kv, vv, qo, ko;
    qv.s = *(const short8*)(qkv + src);
    kv.s = *(const short8*)(qkv + src + 1024);
    vv.s = *(const short8*)(qkv + src + 2048);
#pragma unroll
    for (int p = 0; p < 4; ++p) {
      int i = (d0 >> 1) + p;
      float inv = exp2f(-13.287712379549449f * ((float)(2 * i) * (1.0f / 64.0f)));
      float ang = (float)t * inv;
      float sn, cn;
      sincosf(ang, &sn, &cn);
      float q1 = __bfloat162float(qv.h[2 * p]);
      float q2 = __bfloat162float(qv.h[2 * p + 1]);
      float k1 = __bfloat162float(kv.h[2 * p]);
      float k2 = __bfloat162float(kv.h[2 * p + 1]);
      qo.h[2 * p]     = __float2bfloat16((q1 * cn - q2 * sn) * QSCL);
      qo.h[2 * p + 1] = __float2bfloat16((q1 * sn + q2 * cn) * QSCL);
      ko.h[2 * p]     = __float2bfloat16(k1 * cn - k2 * sn);
      ko.h[2 * p + 1] = __float2bfloat16(k1 * sn + k2 * cn);
    }
    size_t dst = ((size_t)bh * T_CTX + t) * 64 + d0;
    *(short8*)(Qb + dst) = qo.s;
    *(short8*)(Kb + dst) = ko.s;
#pragma unroll
    for (int j = 0; j < 8; ++j) vt[d0 + j][tt] = vv.h[j];
  }
  __syncthreads();
#pragma unroll
  for (int rep = 0; rep < 2; ++rep) {
    int idx = rep * 256 + tid;
    int d = idx >> 3;
    int toff = (idx & 7) * 8;
    BV8 o;
#pragma unroll
    for (int j = 0; j < 8; ++j) o.h[j] = vt[d][toff + j];
    *(short8*)(VTb + ((size_t)bh * 64 + d) * T_CTX + t0 + toff) = o.s;
  }
}

// ---------------- flash attention (causal), 32x32 MFMA, paired-tile barriers ----------------
// Round-11 structure (4 waves = qsub x kh, 64-row balanced slab pairs, k-split,
// fixed-base exp2 softmax, end-of-kernel merge) with TWO KV tiles per barrier:
// buffers = 2 x 32KB (two 16KB tile slots); even global rounds do {barrier; stage g+2,g+3};
// odd rounds are barrier-free (drained by the preceding even barrier). Barriers 33 -> 17.
__global__ __launch_bounds__(256) void flash_attn(const __hip_bfloat16* __restrict__ Qb,
                                                  const __hip_bfloat16* __restrict__ Kb,
                                                  const __hip_bfloat16* __restrict__ VTb,
                                                  __hip_bfloat16* __restrict__ Y) {
  __shared__ __align__(16) char smem[65536];  // 2 bufs x 2 tile-slots x 16KB; merge reuses 33KB
  const int bh = blockIdx.x;
  const int b = bh >> 4, h = bh & 15;
  const int y = blockIdx.y;
  const int jA = 31 - y;            // long slab (64 q-rows at jA*64), tiles jA+1
  const int jB = y;                 // short slab, tiles jB+1 (total 33, g = 0..32)
  const int tid = threadIdx.x;
  const int w = tid >> 6, l = tid & 63;
  const int qsub = w >> 1, kh = w & 1;
  const int l31 = l & 31, hh = l >> 5;
  const int sw7 = (l31 & 7) << 4;
  const int rowb = tid >> 3;          // 0..31 (staging row within 32-row group)
  const int colS = (tid & 7) * 16;

  // stage global-round gg's KV tile (16KB) into slot [(gg>>1)&1][gg&1]
#define STAGE1(gg)                                                                     \
  {                                                                                    \
    const int tt_ = ((gg) <= jA) ? (gg) : (gg) - jA - 1;                               \
    const int kv0_ = tt_ << 6;                                                         \
    char* base_ = smem + (((gg) >> 1) & 1) * 32768 + ((gg) & 1) * 16384;               \
    _Pragma("unroll")                                                                  \
    for (int rnd = 0; rnd < 2; ++rnd) {                                                \
      int row = rnd * 32 + rowb;                                                       \
      int sw = colS ^ ((row & 7) << 4);                                                \
      GLD16((const char*)Kb + (((size_t)bh * T_CTX + kv0_ + row) << 7) + sw,           \
            base_ + rnd * 4096 + w * 1024);                                            \
      GLD16((const char*)VTb + ((((size_t)bh * 64 + row) * T_CTX + kv0_) << 1) + sw,   \
            base_ + 8192 + rnd * 4096 + w * 1024);                                     \
    }                                                                                  \
  }

  // partial O^T per (slab, dt): d = dt*32 + (r&3)+8*(r>>2)+4*hh, q = slab_q0+qsub*32+l31
  f32x16 oA0 = {}, oA1 = {}, oB0 = {}, oB1 = {};
  float lrA = 0.0f, lrB = 0.0f;

  STAGE1(0)
  STAGE1(1)

  int rr = 0;  // global round counter 0..32
#pragma unroll
  for (int ph = 0; ph < 2; ++ph) {
    const int j = ph ? jB : jA;
    const int qglob = j * 64 + qsub * 32 + l31;
    f32x16& od0 = ph ? oB0 : oA0;
    f32x16& od1 = ph ? oB1 : oA1;
    float& lrw = ph ? lrB : lrA;

    // Q as B-operand: lane q = qglob, contraction d = dblk*16 + hh*8 + jj
    short8 qB[4];
#pragma unroll
    for (int dblk = 0; dblk < 4; ++dblk)
      qB[dblk] = *(const short8*)(Qb + ((size_t)bh * T_CTX + qglob) * 64 + dblk * 16 + hh * 8);

    for (int t = 0; t <= j; ++t, ++rr) {
      if ((rr & 1) == 0) {
        __syncthreads();  // tiles rr, rr+1 drained; prior buffer reads complete
        if (rr + 2 <= 32) STAGE1(rr + 2)
        if (rr + 3 <= 32) STAGE1(rr + 3)
      }
      const char* KsB = smem + ((rr >> 1) & 1) * 32768 + (rr & 1) * 16384;
      const char* VsB = KsB + 8192;
      const int kv0 = t << 6;
      const bool lastT = (t == j);

      if (!(lastT && kh > qsub)) {  // skip fully-masked diag wave (uniform, no barriers)
        // K fragments for this wave's k-half: rows kh*32 + l31
        short8 kA[4];
#pragma unroll
        for (int dblk = 0; dblk < 4; ++dblk)
          kA[dblk] = *(const short8*)(KsB + (kh * 32 + l31) * 128 + ((dblk * 32 + hh * 16) ^ sw7));
        // V^T fragments: rows d (both dt), cols = wave's k-half, 2 slices of 16
        short8 vA[2][2];
#pragma unroll
        for (int dt = 0; dt < 2; ++dt)
#pragma unroll
          for (int ks = 0; ks < 2; ++ks)
            vA[dt][ks] = *(const short8*)(VsB + (dt * 32 + l31) * 128 +
                                          ((kh * 64 + ks * 32 + hh * 16) ^ sw7));

        // QK^T: k = kv0 + kh*32 + (r&3)+8*(r>>2)+4*hh, q = qglob
        f32x16 sT = {};
#pragma unroll
        for (int dblk = 0; dblk < 4; ++dblk) {
          __builtin_amdgcn_s_setprio(1);
          sT = __builtin_amdgcn_mfma_f32_32x32x16_bf16(kA[dblk], qB[dblk], sT, 0, 0, 0);
          __builtin_amdgcn_s_setprio(0);
        }
        if (lastT && kh == qsub) {  // diagonal 32x32 block: causal mask
          const int kbase = kv0 + kh * 32 + 4 * hh;
#pragma unroll
          for (int r = 0; r < 16; ++r) {
            int kg = kbase + (r & 3) + 8 * (r >> 2);
            sT[r] = (kg > qglob) ? -1e30f : sT[r];
          }
        }
        // fixed-base softmax: P = exp2(s); per-lane partial l
        float s8[8];
#pragma unroll
        for (int i = 0; i < 8; ++i) {
          sT[i]     = __builtin_amdgcn_exp2f(sT[i]);
          sT[i + 8] = __builtin_amdgcn_exp2f(sT[i + 8]);
          s8[i] = sT[i] + sT[i + 8];
        }
        float ps = ((s8[0] + s8[1]) + (s8[2] + s8[3])) + ((s8[4] + s8[5]) + (s8[6] + s8[7]));
        ps += __shfl_xor(ps, 32);  // merge hh halves (same q)
        lrw += ps;
        // P -> bf16 pairs
        uint32_t wk[8];
#pragma unroll
        for (int i = 0; i < 8; ++i) wk[i] = pkbf(sT[2 * i], sT[2 * i + 1]);
        // PV: 2 k-slices of 16 within the wave's k-half
#pragma unroll
        for (int ks = 0; ks < 2; ++ks) {
          const int base = ks * 4;
          uint32_t own0 = wk[base + 0], own1 = wk[base + 1];
          uint32_t own2 = wk[base + 2], own3 = wk[base + 3];
          uint32_t e0 = (uint32_t)__shfl_xor((int)(hh ? own0 : own2), 32);
          uint32_t e1 = (uint32_t)__shfl_xor((int)(hh ? own1 : own3), 32);
          U32x4 u;
          u.u[0] = hh ? e0 : own0;
          u.u[1] = hh ? e1 : own1;
          u.u[2] = hh ? own2 : e0;
          u.u[3] = hh ? own3 : e1;
          __builtin_amdgcn_s_setprio(1);
          od0 = __builtin_amdgcn_mfma_f32_32x32x16_bf16(vA[0][ks], u.s8, od0, 0, 0, 0);
          od1 = __builtin_amdgcn_mfma_f32_32x32x16_bf16(vA[1][ks], u.s8, od1, 0, 0, 0);
          __builtin_amdgcn_s_setprio(0);
        }
      }
    }
  }

  // ---- cross-wave merge: k-half partners (qsub, kh) <-> (qsub, kh^1); wave owns dt = kh ----
  __syncthreads();  // all staging + LDS reads done; smem free for exchange
  {
    float* exch = (float*)smem;   // 8 slots x 1024 f32 (32q x 32d, XOR-swizzled chunks)
    float* lst = exch + 8192;     // l partials: [slot][32]
    const int slotA = (0 * 2 + qsub) * 2 + kh;
    const int slotB = (1 * 2 + qsub) * 2 + kh;
    const f32x16& nA = kh ? oA0 : oA1;  // non-owned dt = 1-kh
    const f32x16& nB = kh ? oB0 : oB1;
#pragma unroll
    for (int m = 0; m < 4; ++m) {
      int c = ((2 * m + hh) ^ (l31 & 7)) * 4;
      f32x4 va, vb;
#pragma unroll
      for (int i = 0; i < 4; ++i) { va[i] = nA[m * 4 + i]; vb[i] = nB[m * 4 + i]; }
      *(f32x4*)(exch + slotA * 1024 + l31 * 32 + c) = va;
      *(f32x4*)(exch + slotB * 1024 + l31 * 32 + c) = vb;
    }
    if (hh == 0) {
      lst[slotA * 32 + l31] = lrA;
      lst[slotB * 32 + l31] = lrB;
    }
    __syncthreads();
    const int pA = (0 * 2 + qsub) * 2 + (kh ^ 1);
    const int pB = (1 * 2 + qsub) * 2 + (kh ^ 1);
    float ltA = lrA + lst[pA * 32 + l31];
    float ltB = lrB + lst[pB * 32 + l31];
    f32x16& ownA = kh ? oA1 : oA0;
    f32x16& ownB = kh ? oB1 : oB0;
#pragma unroll
    for (int m = 0; m < 4; ++m) {
      int c = ((2 * m + hh) ^ (l31 & 7)) * 4;
      f32x4 aA = *(const f32x4*)(exch + pA * 1024 + l31 * 32 + c);
      f32x4 aB = *(const f32x4*)(exch + pB * 1024 + l31 * 32 + c);
#pragma unroll
      for (int i = 0; i < 4; ++i) { ownA[m * 4 + i] += aA[i]; ownB[m * 4 + i] += aB[i]; }
    }
    // write Y: wave's owned 32 d-cols (kh half), both slabs
#pragma unroll
    for (int sl = 0; sl < 2; ++sl) {
      const f32x16& ov = sl ? ownB : ownA;
      float inv = 1.0f / (sl ? ltB : ltA);
      int q0s = (sl ? jB : jA) * 64 + qsub * 32;
      size_t rowoff = ((size_t)(b * T_CTX + q0s + l31)) * DIM_C + h * 64 + kh * 32;
#pragma unroll
      for (int m = 0; m < 4; ++m) {
        union { ushort4 v; unsigned short us[4]; } st;
#pragma unroll
        for (int i = 0; i < 4; ++i) {
          union { __hip_bfloat16 h2; unsigned short u; } cv;
          cv.h2 = __float2bfloat16(ov[m * 4 + i] * inv);
          st.us[i] = cv.u;
        }
        *(ushort4*)(Y + rowoff + 8 * m + 4 * hh) = st.v;
      }
    }
  }
#undef STAGE1
}

// ---------------- launcher ----------------
extern "C" void kernel_launch(void* const* d_in, const int* in_sizes, int n_in,
                              void* d_out, int out_size, void* d_ws, size_t ws_size,
                              hipStream_t stream) {
  const float* x     = (const float*)d_in[0];
  const float* qkv_w = (const float*)d_in[1];
  const float* out_w = (const float*)d_in[2];
  float* out = (float*)d_out;

  char* ws = (char*)d_ws;
  const size_t MB = 1024 * 1024;
  __hip_bfloat16* xb    = (__hip_bfloat16*)(ws + 0 * MB);
  __hip_bfloat16* wqkvb = (__hip_bfloat16*)(ws + 8 * MB);
  __hip_bfloat16* woutb = (__hip_bfloat16*)(ws + 14 * MB);
  __hip_bfloat16* qkvb  = (__hip_bfloat16*)(ws + 16 * MB);
  __hip_bfloat16* Qb    = (__hip_bfloat16*)(ws + 40 * MB);
  __hip_bfloat16* Kb    = (__hip_bfloat16*)(ws + 48 * MB);
  __hip_bfloat16* VTb   = (__hip_bfloat16*)(ws + 56 * MB);
  __hip_bfloat16* yb    = (__hip_bfloat16*)(ws + 64 * MB);

  cvt_f32_bf16<<<4096, 256, 0, stream>>>(x, xb, 1048576);
  cvt_f32_bf16<<<3072, 256, 0, stream>>>(qkv_w, wqkvb, 786432);
  cvt_f32_bf16<<<1024, 256, 0, stream>>>(out_w, woutb, 262144);

  gemm_bt<__hip_bfloat16><<<dim3(24, 32), 256, 0, stream>>>(xb, wqkvb, qkvb, 4096, 3072, 1024);

  rope_pack<<<dim3(32, 32), 256, 0, stream>>>(qkvb, Qb, Kb, VTb);

  // 16 slab-pairs (31-y, y of 64-row slabs) x 32 bh = 512 blocks, 4 waves each
  flash_attn<<<dim3(NBH, 16), 256, 0, stream>>>(Qb, Kb, VTb, yb);

  gemm_bt<float><<<dim3(8, 32), 256, 0, stream>>>(yb, woutb, out, 4096, 1024, 1024);
}